// Round 5
// baseline (4029.059 us; speedup 1.0000x reference)
//
#include <hip/hip_runtime.h>
#include <math.h>

#define BB 64
#define TT 512
#define EE 128
#define HH 256
#define NK 9

#define XROW 416        // xh row stride (dbl): x at [0,128), h dbl u at 128+u+2*(u>>4) -> max 413
#define RKS  578        // red ks-stride (dbl) = 32 rows * 18 + 2

// ws byte offsets
#define OFF_TICK  524288ULL                      // hx = 2par*2dir*4bs*4096*8 = 512KB
#define OFF_HS    528384ULL
#define OFF_FEATS (528384ULL + 134217728ULL)     // hs = 2*512*256*64*8

// ---------------- init: hx parity0 from h0, zero counters ----------------
__global__ void init_kernel(double* __restrict__ hx, int* __restrict__ tick,
                            const float* __restrict__ h0) {
  int gid = blockIdx.x * 256 + threadIdx.x;
  if (gid < 2 * HH * BB) {                 // 32768
    int d  = gid >> 14;
    int r  = gid & 16383;
    int bs = r >> 12;
    int bb = (r >> 8) & 15;
    int u  = r & 255;
    // hx layout: [par][dir][bs][bb][u], par=0
    hx[(size_t)(d * 4 + bs) * 4096 + bb * 256 + u] =
        (double)h0[d * 16384 + (bs * 16 + bb) * 256 + u];
  }
  if (gid < 256) tick[gid] = 0;
}

// ---------------- persistent recurrent kernel ----------------
// 256 blocks: group g = bid&7 (dir=g>>2, bslice=g&3); hslice bid>>3 owns units
// u0..u0+7. 256 threads = (rr = tid&15, q = tid>>4).
//  - weights k-sliced into REGISTERS: thread (rr, ks=q) owns gate rows rr,rr+16
//    slice ks: Wih dbl [ks*8,ks*8+8), Whh dbl [ks*16,ks*16+16).
//  - per step: all threads accumulate partials hp[2][16 batches]; LDS tree-reduce
//    over 16 k-slices; thread (rr,q) sums rows (rr,rr+16) for batch bb=q;
//    shfl_xor(8) pairs (i,g)<->(f,o); threads rr<8 do pointwise+h store.
// Cross-block h/tickets: relaxed agent atomics (L3-coherent), no fences.
__launch_bounds__(256, 1)
__global__ void recur_kernel(const int* __restrict__ sent, const float* __restrict__ emb,
                             const float* __restrict__ WihF, const float* __restrict__ WhhF,
                             const float* __restrict__ bihF, const float* __restrict__ bhhF,
                             const float* __restrict__ WihB, const float* __restrict__ WhhB,
                             const float* __restrict__ bihB, const float* __restrict__ bhhB,
                             const float* __restrict__ c0,
                             double* __restrict__ hx, int* __restrict__ tick,
                             double* __restrict__ hsout) {
  extern __shared__ double sm[];
  double* xh     = sm;                    // 16 * XROW = 6656 dbl
  double* red    = sm + 16 * XROW;        // 16 * RKS  = 9248 dbl
  double* bias_l = red + 16 * RKS;        // 32 dbl -> total 15936 dbl = 127488 B

  const int tid = threadIdx.x;
  const int g   = blockIdx.x & 7;
  const int dir = g >> 2;
  const int bs  = g & 3;
  const int u0  = (blockIdx.x >> 3) * 8;
  const int rr  = tid & 15;
  const int q   = tid >> 4;     // k-slice for FMA phases; batch index for final/pointwise

  const float* Wih = dir ? WihB : WihF;
  const float* Whh = dir ? WhhB : WhhF;
  const float* bih = dir ? bihB : bihF;
  const float* bhh = dir ? bhhB : bhhF;

  // ---- register-resident weight slices (f64) ----
  // row0 = rr (gate rr>>3 in {0,1} = i,f), row1 = rr+16 (gate +2 in {2,3} = g,o)
  const size_t g0 = (size_t)((rr >> 3) * HH + u0 + (rr & 7));
  const size_t g1 = g0 + 2 * (size_t)HH;
  double2 wx0[4], wx1[4], wh0[8], wh1[8];
  #pragma unroll
  for (int j = 0; j < 4; ++j) {
    wx0[j] = double2{(double)Wih[g0 * EE + q * 8 + 2 * j], (double)Wih[g0 * EE + q * 8 + 2 * j + 1]};
    wx1[j] = double2{(double)Wih[g1 * EE + q * 8 + 2 * j], (double)Wih[g1 * EE + q * 8 + 2 * j + 1]};
  }
  #pragma unroll
  for (int j = 0; j < 8; ++j) {
    wh0[j] = double2{(double)Whh[g0 * HH + q * 16 + 2 * j], (double)Whh[g0 * HH + q * 16 + 2 * j + 1]};
    wh1[j] = double2{(double)Whh[g1 * HH + q * 16 + 2 * j], (double)Whh[g1 * HH + q * 16 + 2 * j + 1]};
  }
  if (tid < 32) {   // row tid: gate = tid>>3, unit offset tid&7
    int gr = (tid >> 3) * HH + u0 + (tid & 7);
    bias_l[tid] = (double)bih[gr] + (double)bhh[gr];
  }
  double creg = 0.0;
  if (rr < 8)   // owner of (unit u0+rr, batch q)
    creg = (double)c0[dir * (BB * HH) + (bs * 16 + q) * HH + u0 + rr];

  // x-staging for time tq: threads rr>=8 (128 of them), bb_s = rank>>3, cp = rank&7
  auto x_stage = [&](int tq) {
    int rank = q * 8 + (rr - 8);         // 0..127
    int bb_s = rank >> 3, cp = rank & 7;
    int tok = sent[(bs * 16 + bb_s) * TT + tq];
    const float4* ep = (const float4*)(emb + (size_t)tok * EE + cp * 16);
    double* dst = xh + bb_s * XROW + cp * 16;
    #pragma unroll
    for (int m = 0; m < 4; ++m) {
      float4 v = ep[m];
      dst[m * 4 + 0] = (double)v.x; dst[m * 4 + 1] = (double)v.y;
      dst[m * 4 + 2] = (double)v.z; dst[m * 4 + 3] = (double)v.w;
    }
  };

  int* cnt = tick + g * 32;

  if (rr >= 8) x_stage(dir ? TT - 1 : 0);
  __syncthreads();

  for (int i = 0; i < TT; ++i) {
    const int tq = dir ? (TT - 1 - i) : i;

    // ---- wait for group step i ----
    if (tid == 0) {
      const int tgt = 32 * i;
      while (__hip_atomic_load(cnt, __ATOMIC_RELAXED, __HIP_MEMORY_SCOPE_AGENT) < tgt) {}
    }
    __syncthreads();

    // ---- issue h loads (L3); latency hides under x-phase FMA ----
    const double* hsrc = hx + (size_t)(((i & 1) * 2 + dir) * 4 + bs) * 4096;
    double hr[16];
    #pragma unroll
    for (int c = 0; c < 16; ++c)
      hr[c] = __hip_atomic_load(hsrc + c * 256 + tid,
                                __ATOMIC_RELAXED, __HIP_MEMORY_SCOPE_AGENT);

    // ---- x-phase: partials over this thread's x k-slice, all 16 batches ----
    double hp0[16], hp1[16];
    #pragma unroll
    for (int bb = 0; bb < 16; ++bb) {
      const double2* xr = (const double2*)(xh + bb * XROW + q * 8);
      double s0 = 0.0, s1 = 0.0;
      #pragma unroll
      for (int j = 0; j < 4; ++j) {
        double2 v = xr[j];
        s0 += v.x * wx0[j].x; s0 += v.y * wx0[j].y;
        s1 += v.x * wx1[j].x; s1 += v.y * wx1[j].y;
      }
      hp0[bb] = s0; hp1[bb] = s1;
    }

    // ---- write h into LDS (compiler waits the loads here) ----
    #pragma unroll
    for (int c = 0; c < 16; ++c)
      xh[c * XROW + 128 + tid + 2 * (tid >> 4)] = hr[c];
    __syncthreads();

    // ---- h-phase: partials over h k-slice (conflict-free: 18*ks spread) ----
    #pragma unroll
    for (int bb = 0; bb < 16; ++bb) {
      const double2* hv = (const double2*)(xh + bb * XROW + 128 + 18 * q);
      double s0 = hp0[bb], s1 = hp1[bb];
      #pragma unroll
      for (int j = 0; j < 8; ++j) {
        double2 v = hv[j];
        s0 += v.x * wh0[j].x; s0 += v.y * wh0[j].y;
        s1 += v.x * wh1[j].x; s1 += v.y * wh1[j].y;
      }
      hp0[bb] = s0; hp1[bb] = s1;
    }

    // ---- reduction: red[ks][row][bb] (row stride 18, ks stride RKS) ----
    #pragma unroll
    for (int p = 0; p < 8; ++p) {
      *(double2*)(red + q * RKS + rr * 18 + 2 * p)        = double2{hp0[2 * p], hp0[2 * p + 1]};
      *(double2*)(red + q * RKS + (rr + 16) * 18 + 2 * p) = double2{hp1[2 * p], hp1[2 * p + 1]};
    }
    __syncthreads();

    // ---- final gate sums: thread (rr,q) -> rows (rr,rr+16), batch bb=q ----
    double su0 = bias_l[rr], su1 = bias_l[rr + 16];
    #pragma unroll
    for (int kk = 0; kk < 16; ++kk) {
      su0 += red[kk * RKS + rr * 18 + q];
      su1 += red[kk * RKS + (rr + 16) * 18 + q];
    }
    // pair exchange: rr<8 holds (i,g); partner rr+8 holds (f,o)
    double p0 = __shfl_xor(su0, 8, 64);
    double p1 = __shfl_xor(su1, 8, 64);

    double hval = 0.0;
    if (rr < 8) {
      double iv = su0, gv = su1, fv = p0, ov = p1;
      double is = 1.0 / (1.0 + exp(-iv));
      double fs = 1.0 / (1.0 + exp(-fv));
      double gs = tanh(gv);
      double os = 1.0 / (1.0 + exp(-ov));
      creg = fs * creg + is * gs;
      hval = os * tanh(creg);
      __hip_atomic_store(hx + (size_t)((((i + 1) & 1) * 2 + dir) * 4 + bs) * 4096
                            + q * 256 + u0 + rr,
                         hval, __ATOMIC_RELAXED, __HIP_MEMORY_SCOPE_AGENT);
    } else if (i + 1 < TT) {
      x_stage(dir ? (TT - 2 - i) : (i + 1));
    }
    __syncthreads();   // per-wave vmcnt(0): hx sc1-stores complete at L3 before signal

    if (tid == 0)
      __hip_atomic_fetch_add(cnt, 1, __ATOMIC_RELAXED, __HIP_MEMORY_SCOPE_AGENT);

    // hsout off the critical path (after signal)
    if (rr < 8)
      hsout[((size_t)(dir * TT + tq) * HH + u0 + rr) * 64 + bs * 16 + q] = hval;
  }
}

// ---------------- feats = [hf|hb] @ Wout^T + bout ----------------
__global__ void feats_kernel(const double* __restrict__ hs, const float* __restrict__ Wout,
                             const float* __restrict__ bout, double* __restrict__ feats) {
  __shared__ double wl[NK * 2 * HH];   // 4608 doubles
  __shared__ double bl[NK];
  int tid = threadIdx.x, t = blockIdx.x;
  for (int idx = tid; idx < NK * 2 * HH; idx += 256) wl[idx] = (double)Wout[idx];
  if (tid < NK) bl[tid] = (double)bout[tid];
  __syncthreads();
  if (tid < 192) {
    int bb = tid & 63, kg = tid >> 6;   // kg 0..2 -> k = kg*3 + j
    double acc0 = bl[kg * 3 + 0], acc1 = bl[kg * 3 + 1], acc2 = bl[kg * 3 + 2];
    for (int d = 0; d < 2; ++d) {
      const double* hp = hs + ((size_t)(d * TT + t) * HH) * 64 + bb;
      const double* w0 = wl + (kg * 3 + 0) * 2 * HH + d * HH;
      const double* w1 = wl + (kg * 3 + 1) * 2 * HH + d * HH;
      const double* w2 = wl + (kg * 3 + 2) * 2 * HH + d * HH;
      for (int u = 0; u < HH; ++u) {
        double hv = hp[(size_t)u * 64];
        acc0 += hv * w0[u];
        acc1 += hv * w1[u];
        acc2 += hv * w2[u];
      }
    }
    double* fp = feats + ((size_t)bb * TT + t) * NK + kg * 3;
    fp[0] = acc0; fp[1] = acc1; fp[2] = acc2;
  }
}

// ---------------- viterbi decode (one block per batch row) ----------------
__global__ void viterbi_kernel(const double* __restrict__ feats, const float* __restrict__ start,
                               const float* __restrict__ endv, const float* __restrict__ trans,
                               int* __restrict__ out) {
  __shared__ double sc[NK];
  __shared__ double tr[NK * NK];
  __shared__ unsigned char hist[TT - 1][16];
  __shared__ unsigned char tags[TT];
  int lane = threadIdx.x, b = blockIdx.x;
  for (int idx = lane; idx < NK * NK; idx += 64) tr[idx] = (double)trans[idx];
  const double* fb = feats + (size_t)b * TT * NK;
  if (lane < NK) sc[lane] = (double)start[lane] + fb[lane];
  __syncthreads();
  double ftn = (lane < NK) ? fb[NK + lane] : 0.0;
  for (int t = 1; t < TT; ++t) {
    double ft = ftn;
    if (t + 1 < TT && lane < NK) ftn = fb[(size_t)(t + 1) * NK + lane];
    double best = -1e300; int arg = 0;
    if (lane < NK) {
      #pragma unroll
      for (int p = 0; p < NK; ++p) {
        double v = sc[p] + tr[p * NK + lane];
        if (v > best) { best = v; arg = p; }   // strict > keeps first index (jnp.argmax)
      }
      hist[t - 1][lane] = (unsigned char)arg;
    }
    __syncthreads();
    if (lane < NK) sc[lane] = best + ft;   // mask is all-true
    __syncthreads();
  }
  if (lane < NK) sc[lane] += (double)endv[lane];
  __syncthreads();
  if (lane == 0) {
    double best = -1e300; int tag = 0;
    for (int n = 0; n < NK; ++n) if (sc[n] > best) { best = sc[n]; tag = n; }
    tags[TT - 1] = (unsigned char)tag;
    for (int t = TT - 2; t >= 0; --t) { tag = hist[t][tag]; tags[t] = (unsigned char)tag; }
  }
  __syncthreads();
  for (int j = lane; j < TT; j += 64) out[b * TT + j] = (int)tags[j];
}

// ---------------- launcher ----------------
extern "C" void kernel_launch(void* const* d_in, const int* in_sizes, int n_in,
                              void* d_out, int out_size, void* d_ws, size_t ws_size,
                              hipStream_t stream) {
  const int*   sent = (const int*)  d_in[0];
  // d_in[1] = mask (all true) -- unused
  const float* emb  = (const float*)d_in[2];
  const float* WihF = (const float*)d_in[3];
  const float* WhhF = (const float*)d_in[4];
  const float* bihF = (const float*)d_in[5];
  const float* bhhF = (const float*)d_in[6];
  const float* WihB = (const float*)d_in[7];
  const float* WhhB = (const float*)d_in[8];
  const float* bihB = (const float*)d_in[9];
  const float* bhhB = (const float*)d_in[10];
  const float* Wout = (const float*)d_in[11];
  const float* bout = (const float*)d_in[12];
  const float* stv  = (const float*)d_in[13];
  const float* env  = (const float*)d_in[14];
  const float* trv  = (const float*)d_in[15];
  const float* h0   = (const float*)d_in[16];
  const float* c0   = (const float*)d_in[17];

  char* ws = (char*)d_ws;
  double* hx    = (double*)ws;                 // [par][dir][bs][bb][u] f64, 512KB
  int*    tick  = (int*)(ws + OFF_TICK);       // 8 counters, stride 32 ints
  double* hs    = (double*)(ws + OFF_HS);      // [dir][t][u][b64] f64
  double* feats = (double*)(ws + OFF_FEATS);   // [b][t][9] f64
  int* out = (int*)d_out;

  hipFuncSetAttribute((const void*)recur_kernel,
                      hipFuncAttributeMaxDynamicSharedMemorySize, 131072);

  init_kernel<<<128, 256, 0, stream>>>(hx, tick, h0);
  recur_kernel<<<256, 256, 127488, stream>>>(sent, emb, WihF, WhhF, bihF, bhhF,
                                             WihB, WhhB, bihB, bhhB, c0, hx, tick, hs);
  feats_kernel<<<TT, 256, 0, stream>>>(hs, Wout, bout, feats);
  viterbi_kernel<<<BB, 64, 0, stream>>>(feats, stv, env, trv, out);
}

// Round 6
// 3644.722 us; speedup vs baseline: 1.1055x; 1.1055x over previous
//
#include <hip/hip_runtime.h>
#include <math.h>

#define BB 64
#define TT 512
#define EE 128
#define HH 256
#define NK 9

// LDS layout (doubles)
#define XS_BB 162                       // x: [bb][q*10 + j], j<8  (bank-spread)
#define HS_BB 290                       // h: [bb][q*18 + j], j<16 (bank-spread)
#define HST_OFF (16 * XS_BB)            // 2592
#define LDS_DBL (HST_OFF + 16 * HS_BB)  // 7232 dbl = 57856 B

// ws byte offsets
#define OFF_TICK  524288ULL                      // hx = 2par*2dir*4bs*4096*8 = 512KB
#define OFF_HS    528384ULL
#define OFF_FEATS (528384ULL + 134217728ULL)     // hs = 2*512*256*64*8

// ---------------- init: hx parity0 from h0, zero counters ----------------
__global__ void init_kernel(double* __restrict__ hx, int* __restrict__ tick,
                            const float* __restrict__ h0) {
  int gid = blockIdx.x * 256 + threadIdx.x;
  if (gid < 2 * HH * BB) {                 // 32768
    int d  = gid >> 14;
    int r  = gid & 16383;
    int bs = r >> 12;
    int bb = (r >> 8) & 15;
    int u  = r & 255;
    hx[(size_t)(d * 4 + bs) * 4096 + bb * 256 + u] =
        (double)h0[d * 16384 + (bs * 16 + bb) * 256 + u];
  }
  if (gid < 256) tick[gid] = 0;
}

// ---------------- persistent recurrent kernel ----------------
// 256 blocks: group g = bid&7 (dir=g>>2, bslice=g&3); hslice bid>>3 owns units
// u0..u0+7. Threads: w=tid>>6, lane=tid&63, q=lane&15 (k-slice / batch), p=lane>>4,
// rs = w+4p (row-set 0..15): rows (rs, rs+16) = (i,g) for rs<8, (f,o) for rs>=8.
// Weights live in REGISTERS (k-slice q). Per step: per-thread partials over all
// 16 batches -> shfl_xor reduce-scatter over q-bits (lane ends with bb=q) ->
// shfl_xor(32) pairs (i,g)<->(f,o) intra-wave -> p<2 lanes do pointwise.
// Cross-block h/tickets: relaxed agent atomics (L3-coherent), no fences.
__launch_bounds__(256, 1)
__global__ void recur_kernel(const int* __restrict__ sent, const float* __restrict__ emb,
                             const float* __restrict__ WihF, const float* __restrict__ WhhF,
                             const float* __restrict__ bihF, const float* __restrict__ bhhF,
                             const float* __restrict__ WihB, const float* __restrict__ WhhB,
                             const float* __restrict__ bihB, const float* __restrict__ bhhB,
                             const float* __restrict__ c0v,
                             double* __restrict__ hx, int* __restrict__ tick,
                             double* __restrict__ hsout) {
  extern __shared__ double sm[];
  double* xs  = sm;              // 16 * XS_BB
  double* hst = sm + HST_OFF;    // 16 * HS_BB

  const int tid  = threadIdx.x;
  const int g    = blockIdx.x & 7;
  const int dir  = g >> 2;
  const int bs   = g & 3;
  const int u0   = (blockIdx.x >> 3) * 8;
  const int w    = tid >> 6;
  const int lane = tid & 63;
  const int q    = lane & 15;
  const int p    = lane >> 4;
  const int rs   = w + 4 * p;    // 0..15

  const float* Wih = dir ? WihB : WihF;
  const float* Whh = dir ? WhhB : WhhF;
  const float* bih = dir ? bihB : bihF;
  const float* bhh = dir ? bhhB : bhhF;

  // ---- register-resident weight k-slices (f64) ----
  const size_t r0 = (size_t)((rs >> 3) * HH + u0 + (rs & 7));   // gate i (rs<8) / f
  const size_t r1 = r0 + 2 * (size_t)HH;                        // gate g / o
  double2 wx0[4], wx1[4], wh0[8], wh1[8];
  #pragma unroll
  for (int j = 0; j < 4; ++j) {
    wx0[j] = double2{(double)Wih[r0 * EE + q * 8 + 2 * j], (double)Wih[r0 * EE + q * 8 + 2 * j + 1]};
    wx1[j] = double2{(double)Wih[r1 * EE + q * 8 + 2 * j], (double)Wih[r1 * EE + q * 8 + 2 * j + 1]};
  }
  #pragma unroll
  for (int j = 0; j < 8; ++j) {
    wh0[j] = double2{(double)Whh[r0 * HH + q * 16 + 2 * j], (double)Whh[r0 * HH + q * 16 + 2 * j + 1]};
    wh1[j] = double2{(double)Whh[r1 * HH + q * 16 + 2 * j], (double)Whh[r1 * HH + q * 16 + 2 * j + 1]};
  }
  const double bias0 = (double)bih[r0] + (double)bhh[r0];
  const double bias1 = (double)bih[r1] + (double)bhh[r1];

  double creg = 0.0;
  if (p < 2)   // owner of (unit u0+rs, batch q)
    creg = (double)c0v[dir * (BB * HH) + (bs * 16 + q) * HH + u0 + rs];

  // x-staging by p>=2 lanes (128 threads): rank -> (bb_s, qq), stages q-blocks qq,qq+8
  auto x_stage = [&](int tq) {
    int rank = w * 32 + (p - 2) * 16 + q;   // 0..127
    int bb_s = rank >> 3, qq = rank & 7;
    int tok = sent[(bs * 16 + bb_s) * TT + tq];
    const float4* ep = (const float4*)(emb + (size_t)tok * EE);
    float4 v0 = ep[qq * 2], v1 = ep[qq * 2 + 1];
    float4 v2 = ep[(qq + 8) * 2], v3 = ep[(qq + 8) * 2 + 1];
    double* d0 = xs + bb_s * XS_BB + qq * 10;
    double* d1 = xs + bb_s * XS_BB + (qq + 8) * 10;
    d0[0] = (double)v0.x; d0[1] = (double)v0.y; d0[2] = (double)v0.z; d0[3] = (double)v0.w;
    d0[4] = (double)v1.x; d0[5] = (double)v1.y; d0[6] = (double)v1.z; d0[7] = (double)v1.w;
    d1[0] = (double)v2.x; d1[1] = (double)v2.y; d1[2] = (double)v2.z; d1[3] = (double)v2.w;
    d1[4] = (double)v3.x; d1[5] = (double)v3.y; d1[6] = (double)v3.z; d1[7] = (double)v3.w;
  };

  int* cnt = tick + g * 32;

  if (p >= 2) x_stage(dir ? TT - 1 : 0);
  __syncthreads();

  for (int i = 0; i < TT; ++i) {
    const int tq = dir ? (TT - 1 - i) : i;

    // ---- x-phase partials (k-slice q, all 16 batches) — hides the wait ----
    double hp0[16], hp1[16];
    #pragma unroll
    for (int bb = 0; bb < 16; ++bb) {
      const double2* xr = (const double2*)(xs + bb * XS_BB + q * 10);
      double s0 = 0.0, s1 = 0.0;
      #pragma unroll
      for (int j = 0; j < 4; ++j) {
        double2 v = xr[j];
        s0 += v.x * wx0[j].x; s0 += v.y * wx0[j].y;
        s1 += v.x * wx1[j].x; s1 += v.y * wx1[j].y;
      }
      hp0[bb] = s0; hp1[bb] = s1;
    }

    // ---- wait for group step i ----
    if (tid == 0) {
      const int tgt = 32 * i;
      while (__hip_atomic_load(cnt, __ATOMIC_RELAXED, __HIP_MEMORY_SCOPE_AGENT) < tgt) {}
    }
    __syncthreads();

    // ---- h: L3 load (coalesced) -> LDS k-slice layout ----
    const double* hsrc = hx + (size_t)(((i & 1) * 2 + dir) * 4 + bs) * 4096;
    double hr[16];
    #pragma unroll
    for (int c = 0; c < 16; ++c)
      hr[c] = __hip_atomic_load(hsrc + c * 256 + tid,
                                __ATOMIC_RELAXED, __HIP_MEMORY_SCOPE_AGENT);
    #pragma unroll
    for (int c = 0; c < 16; ++c)
      hst[c * HS_BB + (tid >> 4) * 18 + (tid & 15)] = hr[c];
    __syncthreads();

    // ---- h-phase partials (k-slice q) ----
    #pragma unroll
    for (int bb = 0; bb < 16; ++bb) {
      const double2* hv = (const double2*)(hst + bb * HS_BB + q * 18);
      double s0 = hp0[bb], s1 = hp1[bb];
      #pragma unroll
      for (int j = 0; j < 8; ++j) {
        double2 v = hv[j];
        s0 += v.x * wh0[j].x; s0 += v.y * wh0[j].y;
        s1 += v.x * wh1[j].x; s1 += v.y * wh1[j].y;
      }
      hp0[bb] = s0; hp1[bb] = s1;
    }

    // ---- reduce-scatter over q bits (lane ends with bb = q), static indices ----
    double sA[8], sB[8];
    {
      const int b = lane & 1;
      #pragma unroll
      for (int m = 0; m < 8; ++m) {
        double k0 = b ? hp0[2 * m + 1] : hp0[2 * m];
        double d0 = b ? hp0[2 * m]     : hp0[2 * m + 1];
        sA[m] = k0 + __shfl_xor(d0, 1, 64);
        double k1 = b ? hp1[2 * m + 1] : hp1[2 * m];
        double d1 = b ? hp1[2 * m]     : hp1[2 * m + 1];
        sB[m] = k1 + __shfl_xor(d1, 1, 64);
      }
    }
    double tA[4], tB[4];
    {
      const int b = (lane >> 1) & 1;
      #pragma unroll
      for (int m = 0; m < 4; ++m) {
        double k0 = b ? sA[2 * m + 1] : sA[2 * m];
        double d0 = b ? sA[2 * m]     : sA[2 * m + 1];
        tA[m] = k0 + __shfl_xor(d0, 2, 64);
        double k1 = b ? sB[2 * m + 1] : sB[2 * m];
        double d1 = b ? sB[2 * m]     : sB[2 * m + 1];
        tB[m] = k1 + __shfl_xor(d1, 2, 64);
      }
    }
    double uA[2], uB[2];
    {
      const int b = (lane >> 2) & 1;
      #pragma unroll
      for (int m = 0; m < 2; ++m) {
        double k0 = b ? tA[2 * m + 1] : tA[2 * m];
        double d0 = b ? tA[2 * m]     : tA[2 * m + 1];
        uA[m] = k0 + __shfl_xor(d0, 4, 64);
        double k1 = b ? tB[2 * m + 1] : tB[2 * m];
        double d1 = b ? tB[2 * m]     : tB[2 * m + 1];
        uB[m] = k1 + __shfl_xor(d1, 4, 64);
      }
    }
    double su0, su1;
    {
      const int b = (lane >> 3) & 1;
      double k0 = b ? uA[1] : uA[0];
      double d0 = b ? uA[0] : uA[1];
      su0 = k0 + __shfl_xor(d0, 8, 64) + bias0;
      double k1 = b ? uB[1] : uB[0];
      double d1 = b ? uB[0] : uB[1];
      su1 = k1 + __shfl_xor(d1, 8, 64) + bias1;
    }
    // pair exchange: (i,g) lanes (p<2) <-> (f,o) lanes (p>=2), same wave
    double po0 = __shfl_xor(su0, 32, 64);
    double po1 = __shfl_xor(su1, 32, 64);

    double hval = 0.0;
    if (p < 2) {
      double iv = su0, gv = su1, fv = po0, ov = po1;
      double is = 1.0 / (1.0 + exp(-iv));
      double fs = 1.0 / (1.0 + exp(-fv));
      double gs = tanh(gv);
      double os = 1.0 / (1.0 + exp(-ov));
      creg = fs * creg + is * gs;
      hval = os * tanh(creg);
      __hip_atomic_store(hx + (size_t)((((i + 1) & 1) * 2 + dir) * 4 + bs) * 4096
                            + q * 256 + u0 + rs,
                         hval, __ATOMIC_RELAXED, __HIP_MEMORY_SCOPE_AGENT);
    } else if (i + 1 < TT) {
      x_stage(dir ? (TT - 2 - i) : (i + 1));
    }
    __syncthreads();   // per-wave vmcnt(0): hx sc1-stores complete at L3 before signal

    if (tid == 0)
      __hip_atomic_fetch_add(cnt, 1, __ATOMIC_RELAXED, __HIP_MEMORY_SCOPE_AGENT);

    // hsout off the critical path (after signal)
    if (p < 2)
      hsout[((size_t)(dir * TT + tq) * HH + u0 + rs) * 64 + bs * 16 + q] = hval;
  }
}

// ---------------- feats = [hf|hb] @ Wout^T + bout ----------------
__global__ void feats_kernel(const double* __restrict__ hs, const float* __restrict__ Wout,
                             const float* __restrict__ bout, double* __restrict__ feats) {
  __shared__ double wl[NK * 2 * HH];   // 4608 doubles
  __shared__ double bl[NK];
  int tid = threadIdx.x, t = blockIdx.x;
  for (int idx = tid; idx < NK * 2 * HH; idx += 256) wl[idx] = (double)Wout[idx];
  if (tid < NK) bl[tid] = (double)bout[tid];
  __syncthreads();
  if (tid < 192) {
    int bb = tid & 63, kg = tid >> 6;   // kg 0..2 -> k = kg*3 + j
    double acc0 = bl[kg * 3 + 0], acc1 = bl[kg * 3 + 1], acc2 = bl[kg * 3 + 2];
    for (int d = 0; d < 2; ++d) {
      const double* hp = hs + ((size_t)(d * TT + t) * HH) * 64 + bb;
      const double* w0 = wl + (kg * 3 + 0) * 2 * HH + d * HH;
      const double* w1 = wl + (kg * 3 + 1) * 2 * HH + d * HH;
      const double* w2 = wl + (kg * 3 + 2) * 2 * HH + d * HH;
      for (int u = 0; u < HH; ++u) {
        double hv = hp[(size_t)u * 64];
        acc0 += hv * w0[u];
        acc1 += hv * w1[u];
        acc2 += hv * w2[u];
      }
    }
    double* fp = feats + ((size_t)bb * TT + t) * NK + kg * 3;
    fp[0] = acc0; fp[1] = acc1; fp[2] = acc2;
  }
}

// ---------------- viterbi decode (one block per batch row) ----------------
__global__ void viterbi_kernel(const double* __restrict__ feats, const float* __restrict__ start,
                               const float* __restrict__ endv, const float* __restrict__ trans,
                               int* __restrict__ out) {
  __shared__ double sc[NK];
  __shared__ double tr[NK * NK];
  __shared__ unsigned char hist[TT - 1][16];
  __shared__ unsigned char tags[TT];
  int lane = threadIdx.x, b = blockIdx.x;
  for (int idx = lane; idx < NK * NK; idx += 64) tr[idx] = (double)trans[idx];
  const double* fb = feats + (size_t)b * TT * NK;
  if (lane < NK) sc[lane] = (double)start[lane] + fb[lane];
  __syncthreads();
  double ftn = (lane < NK) ? fb[NK + lane] : 0.0;
  for (int t = 1; t < TT; ++t) {
    double ft = ftn;
    if (t + 1 < TT && lane < NK) ftn = fb[(size_t)(t + 1) * NK + lane];
    double best = -1e300; int arg = 0;
    if (lane < NK) {
      #pragma unroll
      for (int p = 0; p < NK; ++p) {
        double v = sc[p] + tr[p * NK + lane];
        if (v > best) { best = v; arg = p; }   // strict > keeps first index (jnp.argmax)
      }
      hist[t - 1][lane] = (unsigned char)arg;
    }
    __syncthreads();
    if (lane < NK) sc[lane] = best + ft;   // mask is all-true
    __syncthreads();
  }
  if (lane < NK) sc[lane] += (double)endv[lane];
  __syncthreads();
  if (lane == 0) {
    double best = -1e300; int tag = 0;
    for (int n = 0; n < NK; ++n) if (sc[n] > best) { best = sc[n]; tag = n; }
    tags[TT - 1] = (unsigned char)tag;
    for (int t = TT - 2; t >= 0; --t) { tag = hist[t][tag]; tags[t] = (unsigned char)tag; }
  }
  __syncthreads();
  for (int j = lane; j < TT; j += 64) out[b * TT + j] = (int)tags[j];
}

// ---------------- launcher ----------------
extern "C" void kernel_launch(void* const* d_in, const int* in_sizes, int n_in,
                              void* d_out, int out_size, void* d_ws, size_t ws_size,
                              hipStream_t stream) {
  const int*   sent = (const int*)  d_in[0];
  // d_in[1] = mask (all true) -- unused
  const float* emb  = (const float*)d_in[2];
  const float* WihF = (const float*)d_in[3];
  const float* WhhF = (const float*)d_in[4];
  const float* bihF = (const float*)d_in[5];
  const float* bhhF = (const float*)d_in[6];
  const float* WihB = (const float*)d_in[7];
  const float* WhhB = (const float*)d_in[8];
  const float* bihB = (const float*)d_in[9];
  const float* bhhB = (const float*)d_in[10];
  const float* Wout = (const float*)d_in[11];
  const float* bout = (const float*)d_in[12];
  const float* stv  = (const float*)d_in[13];
  const float* env  = (const float*)d_in[14];
  const float* trv  = (const float*)d_in[15];
  const float* h0   = (const float*)d_in[16];
  const float* c0   = (const float*)d_in[17];

  char* ws = (char*)d_ws;
  double* hx    = (double*)ws;                 // [par][dir][bs][bb][u] f64, 512KB
  int*    tick  = (int*)(ws + OFF_TICK);       // 8 counters, stride 32 ints
  double* hs    = (double*)(ws + OFF_HS);      // [dir][t][u][b64] f64
  double* feats = (double*)(ws + OFF_FEATS);   // [b][t][9] f64
  int* out = (int*)d_out;

  hipFuncSetAttribute((const void*)recur_kernel,
                      hipFuncAttributeMaxDynamicSharedMemorySize, 65536);

  init_kernel<<<128, 256, 0, stream>>>(hx, tick, h0);
  recur_kernel<<<256, 256, LDS_DBL * 8, stream>>>(sent, emb, WihF, WhhF, bihF, bhhF,
                                                  WihB, WhhB, bihB, bhhB, c0, hx, tick, hs);
  feats_kernel<<<TT, 256, 0, stream>>>(hs, Wout, bout, feats);
  viterbi_kernel<<<BB, 64, 0, stream>>>(feats, stv, env, trv, out);
}